// Round 1
// baseline (4230.944 us; speedup 1.0000x reference)
//
#include <hip/hip_runtime.h>
#include <math.h>

#define NB 64
#define NN 207
#define NT 48
#define NF 6
#define NH 64
#define NSEQ (NB*NN)          // 13248
#define SEQ_STRIDE (NT*NH)    // 3072

// ---------------- GCN (both layers fused, one block per (b,t)) ----------------
#define H1S 212  // padded stride for h1T [64][212]; 212*4B is 16B-multiple, decent bank spread
#define GCN_LDS_FLOATS (64*H1S + 64*64 + NN*NF + NF*64 + 64 + 64 + 64 + 64)

__global__ __launch_bounds__(256, 2) void gcn_kernel(
    const float* __restrict__ x, const float* __restrict__ W1, const float* __restrict__ b1,
    const float* __restrict__ W2, const float* __restrict__ b2, float* __restrict__ seqx)
{
  extern __shared__ float sm[];
  float* h1T = sm;                      // [64 feat][212]  (feature-major, node-minor)
  float* W2s = h1T + 64*H1S;            // [64 k][64 h]
  float* xs  = W2s + 64*64;             // [207][6]
  float* W1s = xs  + NN*NF;             // [6][64]
  float* b1s = W1s + NF*64;             // 64
  float* b2s = b1s + 64;                // 64
  float* S1  = b2s + 64;                // 64
  float* S2  = S1  + 64;                // 64

  const int tid = threadIdx.x;
  const int t = blockIdx.x, b = blockIdx.y;
  const float inv = 1.0f/208.0f;

  // ---- stage ----
  for (int i=tid;i<64*64;i+=256) W2s[i]=W2[i];
  for (int i=tid;i<NF*64;i+=256) W1s[i]=W1[i];
  if (tid<64){ b1s[tid]=b1[tid]; b2s[tid]=b2[tid]; S1[tid]=0.f; S2[tid]=0.f; }
  {
    const float* xb = x + (size_t)b*NN*NT*NF + (size_t)t*NF;
    for (int i=tid;i<NN*NF;i+=256){ int n=i/NF, f=i-n*NF; xs[i] = xb[(size_t)n*NT*NF + f]; }
  }
  // zero pad columns n=207..211 so phase-2 float4 reads are clean zeros
  for (int i=tid;i<64*5;i+=256){ int h=i/5, c=i-h*5; h1T[h*H1S + NN + c] = 0.f; }
  __syncthreads();

  // ---- phase 1: Y1 = x @ W1, stored transposed h1T[h][n] ----
  #pragma unroll 1
  for (int p=0;p<4;p++){
    int tile = p*256 + tid;             // 832 tiles: nt in [0,52), ht in [0,16)
    if (tile < 832){
      int nt = tile>>4, ht = tile&15;
      #pragma unroll
      for (int i=0;i<4;i++){
        int n = 4*nt+i;
        if (n < NN){
          float a0=0.f,a1=0.f,a2=0.f,a3=0.f;
          #pragma unroll
          for (int f=0;f<NF;f++){
            float xv = xs[n*NF+f];
            float4 wv = *(const float4*)&W1s[f*64 + 4*ht];
            a0 += xv*wv.x; a1 += xv*wv.y; a2 += xv*wv.z; a3 += xv*wv.w;
          }
          h1T[(4*ht+0)*H1S+n]=a0; h1T[(4*ht+1)*H1S+n]=a1;
          h1T[(4*ht+2)*H1S+n]=a2; h1T[(4*ht+3)*H1S+n]=a3;
        }
      }
    }
  }
  __syncthreads();

  // ---- S1[h] = sum_n Y1[n][h] ----
  {
    int h = tid & 63, grp = tid >> 6;
    float ps = 0.f;
    for (int n=grp; n<NN; n+=4) ps += h1T[h*H1S+n];
    atomicAdd(&S1[h], ps);
  }
  __syncthreads();

  // ---- h1 = relu((Y1 + S1)/208 + b1), in place ----
  for (int e=tid; e<64*NN; e+=256){
    int h = e/NN, n = e - h*NN;
    float v = (h1T[h*H1S+n] + S1[h])*inv + b1s[h];
    h1T[h*H1S+n] = v>0.f ? v : 0.f;
  }
  __syncthreads();

  // ---- phase 2: Y2 = h1 @ W2 (register-tiled 4n x 4h), S2 partials ----
  float acc[4][16];
  #pragma unroll
  for (int p=0;p<4;p++){
    #pragma unroll
    for (int e=0;e<16;e++) acc[p][e]=0.f;
    int tile = p*256 + tid;
    if (tile < 832){
      int nt = tile>>4, ht = tile&15;
      const float* arow = h1T + 4*nt;
      const float* wrow = W2s + 4*ht;
      #pragma unroll 4
      for (int k=0;k<64;k++){
        float4 a = *(const float4*)(arow + k*H1S);
        float4 w = *(const float4*)(wrow + k*64);
        acc[p][ 0] += a.x*w.x; acc[p][ 1] += a.x*w.y; acc[p][ 2] += a.x*w.z; acc[p][ 3] += a.x*w.w;
        acc[p][ 4] += a.y*w.x; acc[p][ 5] += a.y*w.y; acc[p][ 6] += a.y*w.z; acc[p][ 7] += a.y*w.w;
        acc[p][ 8] += a.z*w.x; acc[p][ 9] += a.z*w.y; acc[p][10] += a.z*w.z; acc[p][11] += a.z*w.w;
        acc[p][12] += a.w*w.x; acc[p][13] += a.w*w.y; acc[p][14] += a.w*w.z; acc[p][15] += a.w*w.w;
      }
      #pragma unroll
      for (int j=0;j<4;j++){ // pad rows contribute exact zeros
        float ps = acc[p][j] + acc[p][4+j] + acc[p][8+j] + acc[p][12+j];
        atomicAdd(&S2[4*ht+j], ps);
      }
    }
  }
  __syncthreads();

  // ---- h2 = relu((Y2 + S2)/208 + b2) -> seq_x[(b*207+n)*3072 + t*64 + h] ----
  const size_t outbase = ((size_t)b*NN)*SEQ_STRIDE + (size_t)t*NH;
  #pragma unroll
  for (int p=0;p<4;p++){
    int tile = p*256 + tid;
    if (tile < 832){
      int nt = tile>>4, ht = tile&15;
      #pragma unroll
      for (int i=0;i<4;i++){
        int n = 4*nt+i;
        if (n < NN){
          float4 o;
          float v0 = (acc[p][i*4+0] + S2[4*ht+0])*inv + b2s[4*ht+0];
          float v1 = (acc[p][i*4+1] + S2[4*ht+1])*inv + b2s[4*ht+1];
          float v2 = (acc[p][i*4+2] + S2[4*ht+2])*inv + b2s[4*ht+2];
          float v3 = (acc[p][i*4+3] + S2[4*ht+3])*inv + b2s[4*ht+3];
          o.x = v0>0.f?v0:0.f; o.y = v1>0.f?v1:0.f; o.z = v2>0.f?v2:0.f; o.w = v3>0.f?v3:0.f;
          *(float4*)&seqx[outbase + (size_t)n*SEQ_STRIDE + 4*ht] = o;
        }
      }
    }
  }
}

// ---------------- LSTM (persistent per 64-sequence group) ----------------
// wave w: q=w&1 (0: x-part W_ih, 1: h-part W_hh); p=w>>1 (0: rows i,f; 1: rows g,o)
// lane l holds weight rows ra=l+128p, rb=ra+64 in VGPRs (128 regs), loaded once.
#define LSTM_LDS_FLOATS (64*68 + 64*68 + 64*64 + 256*65)

__global__ __launch_bounds__(256, 1) void lstm_kernel(
    const float* __restrict__ seqx, const float* __restrict__ Wih, const float* __restrict__ Whh,
    const float* __restrict__ bih, const float* __restrict__ bhh,
    const float* __restrict__ Wfc, const float* __restrict__ bfc, float* __restrict__ out)
{
  extern __shared__ float sm[];
  float* xbuf = sm;              // [64 s][68]
  float* hbuf = xbuf + 64*68;    // [64 s][68]
  float* cbuf = hbuf + 64*68;    // [64 s][64]
  float* gbuf = cbuf + 64*64;    // [256 r][65]

  const int tid = threadIdx.x;
  const int l = tid & 63, w = tid >> 6;
  const int p = w >> 1, q = w & 1;
  const int ra = l + 128*p, rb = ra + 64;
  const float* Wsel = q ? Whh : Wih;
  const int s0 = blockIdx.x * 64;

  float Wa[64], Wb[64];
  #pragma unroll
  for (int k=0;k<64;k++) Wa[k] = Wsel[ra*64+k];
  #pragma unroll
  for (int k=0;k<64;k++) Wb[k] = Wsel[rb*64+k];
  const float ba = q ? 0.f : (bih[ra]+bhh[ra]);   // bias seeded once per (row,step) by x-waves
  const float bb = q ? 0.f : (bih[rb]+bhh[rb]);

  for (int i=tid;i<64*68;i+=256) hbuf[i]=0.f;
  for (int i=tid;i<64*64;i+=256) cbuf[i]=0.f;
  for (int i=tid;i<256*65;i+=256) gbuf[i]=0.f;
  { // stage x for t=0: thread -> (seq=tid>>2, 16-float chunk kq=tid&3)
    const int ss = tid>>2, kq = tid&3;
    const float4* gp = (const float4*)(seqx + (size_t)(s0+ss)*SEQ_STRIDE + kq*16);
    float4* dp = (float4*)(xbuf + ss*68 + kq*16);
    dp[0]=gp[0]; dp[1]=gp[1]; dp[2]=gp[2]; dp[3]=gp[3];
  }
  __syncthreads();

  const int uj = tid & 63, usg = tid >> 6;

  for (int t=0;t<NT;t++){
    const float* src = q ? hbuf : xbuf;
    // gate GEMV: each wave, for every seq, dots its 2 weight rows against x_t or h_{t-1}
    #pragma unroll 1
    for (int s=0;s<64;s++){
      float a0=ba, a1=0.f, c0=bb, c1=0.f;
      const float* sp = src + s*68;
      #pragma unroll
      for (int kc=0;kc<16;kc+=2){
        float4 v = *(const float4*)(sp + kc*4);
        float4 u = *(const float4*)(sp + kc*4 + 4);
        a0 += v.x*Wa[4*kc+0] + v.y*Wa[4*kc+1] + v.z*Wa[4*kc+2] + v.w*Wa[4*kc+3];
        c0 += v.x*Wb[4*kc+0] + v.y*Wb[4*kc+1] + v.z*Wb[4*kc+2] + v.w*Wb[4*kc+3];
        a1 += u.x*Wa[4*kc+4] + u.y*Wa[4*kc+5] + u.z*Wa[4*kc+6] + u.w*Wa[4*kc+7];
        c1 += u.x*Wb[4*kc+4] + u.y*Wb[4*kc+5] + u.z*Wb[4*kc+6] + u.w*Wb[4*kc+7];
      }
      atomicAdd(&gbuf[ra*65+s], a0+a1);
      atomicAdd(&gbuf[rb*65+s], c0+c1);
    }
    __syncthreads();
    // update: thread (dim uj, seq-group usg) handles 16 seqs
    #pragma unroll 1
    for (int si=0; si<16; si++){
      int s = si*4 + usg;
      float gi = gbuf[(uj     )*65 + s];
      float gf = gbuf[(uj+  64)*65 + s];
      float gg = gbuf[(uj+ 128)*65 + s];
      float go = gbuf[(uj+ 192)*65 + s];
      gbuf[(uj)*65+s]=0.f; gbuf[(uj+64)*65+s]=0.f; gbuf[(uj+128)*65+s]=0.f; gbuf[(uj+192)*65+s]=0.f;
      float c = cbuf[s*64+uj];
      float ig = 1.f/(1.f+expf(-gi));
      float fg = 1.f/(1.f+expf(-gf));
      float og = 1.f/(1.f+expf(-go));
      float gt = tanhf(gg);
      c = fg*c + ig*gt;
      cbuf[s*64+uj] = c;
      hbuf[s*68+uj] = og*tanhf(c);
    }
    if (t+1 < NT){ // stage next x (xbuf consumers finished at the post-GEMV barrier)
      const int ss = tid>>2, kq = tid&3;
      const float4* gp = (const float4*)(seqx + (size_t)(s0+ss)*SEQ_STRIDE + (size_t)(t+1)*NH + kq*16);
      float4* dp = (float4*)(xbuf + ss*68 + kq*16);
      dp[0]=gp[0]; dp[1]=gp[1]; dp[2]=gp[2]; dp[3]=gp[3];
    }
    __syncthreads();
  }

  // epilogue: out[seq] = h_T . W_fc + b_fc
  if (tid < 64){
    float a = bfc[0];
    #pragma unroll 8
    for (int k=0;k<64;k++) a += hbuf[tid*68+k]*Wfc[k];
    out[s0+tid] = a;
  }
}

extern "C" void kernel_launch(void* const* d_in, const int* in_sizes, int n_in,
                              void* d_out, int out_size, void* d_ws, size_t ws_size,
                              hipStream_t stream) {
  const float* x   = (const float*)d_in[0];
  // d_in[1], d_in[2] (N1, N2): structurally dead — sigmoid(N1@N2)>0 is all-ones.
  const float* W1  = (const float*)d_in[3];
  const float* b1  = (const float*)d_in[4];
  const float* W2  = (const float*)d_in[5];
  const float* b2  = (const float*)d_in[6];
  const float* Wih = (const float*)d_in[7];
  const float* Whh = (const float*)d_in[8];
  const float* bih = (const float*)d_in[9];
  const float* bhh = (const float*)d_in[10];
  const float* Wfc = (const float*)d_in[11];
  const float* bfc = (const float*)d_in[12];
  float* seqx = (float*)d_ws;           // [13248 seq][48 t][64 h] fp32 = 162.8 MB
  float* out  = (float*)d_out;          // [13248] fp32

  const int gcn_lds  = GCN_LDS_FLOATS  * 4;
  const int lstm_lds = LSTM_LDS_FLOATS * 4;
  hipFuncSetAttribute((const void*)gcn_kernel,  hipFuncAttributeMaxDynamicSharedMemorySize, gcn_lds);
  hipFuncSetAttribute((const void*)lstm_kernel, hipFuncAttributeMaxDynamicSharedMemorySize, lstm_lds);

  gcn_kernel<<<dim3(NT, NB), 256, gcn_lds, stream>>>(x, W1, b1, W2, b2, seqx);
  lstm_kernel<<<NSEQ/64, 256, lstm_lds, stream>>>(seqx, Wih, Whh, bih, bhh, Wfc, bfc, out);
}

// Round 2
// 1314.574 us; speedup vs baseline: 3.2185x; 3.2185x over previous
//
#include <hip/hip_runtime.h>
#include <math.h>

#define NB 64
#define NN 207
#define NT 48
#define NF 6
#define NH 64
#define NSEQ (NB*NN)          // 13248
#define SEQ_STRIDE (NT*NH)    // 3072

// ---------------- GCN (both layers fused, one block per (b,t)) ----------------
#define H1S 212
#define GCN_LDS_FLOATS (64*H1S + 64*64 + NN*NF + NF*64 + 64 + 64 + 64 + 64)

__global__ __launch_bounds__(256, 2) void gcn_kernel(
    const float* __restrict__ x, const float* __restrict__ W1, const float* __restrict__ b1,
    const float* __restrict__ W2, const float* __restrict__ b2, float* __restrict__ seqx)
{
  extern __shared__ float sm[];
  float* h1T = sm;                      // [64 feat][212]
  float* W2s = h1T + 64*H1S;            // [64 k][64 h]
  float* xs  = W2s + 64*64;             // [207][6]
  float* W1s = xs  + NN*NF;             // [6][64]
  float* b1s = W1s + NF*64;
  float* b2s = b1s + 64;
  float* S1  = b2s + 64;
  float* S2  = S1  + 64;

  const int tid = threadIdx.x;
  const int t = blockIdx.x, b = blockIdx.y;
  const float inv = 1.0f/208.0f;

  for (int i=tid;i<64*64;i+=256) W2s[i]=W2[i];
  for (int i=tid;i<NF*64;i+=256) W1s[i]=W1[i];
  if (tid<64){ b1s[tid]=b1[tid]; b2s[tid]=b2[tid]; S1[tid]=0.f; S2[tid]=0.f; }
  {
    const float* xb = x + (size_t)b*NN*NT*NF + (size_t)t*NF;
    for (int i=tid;i<NN*NF;i+=256){ int n=i/NF, f=i-n*NF; xs[i] = xb[(size_t)n*NT*NF + f]; }
  }
  for (int i=tid;i<64*5;i+=256){ int h=i/5, c=i-h*5; h1T[h*H1S + NN + c] = 0.f; }
  __syncthreads();

  #pragma unroll 1
  for (int p=0;p<4;p++){
    int tile = p*256 + tid;
    if (tile < 832){
      int nt = tile>>4, ht = tile&15;
      #pragma unroll
      for (int i=0;i<4;i++){
        int n = 4*nt+i;
        if (n < NN){
          float a0=0.f,a1=0.f,a2=0.f,a3=0.f;
          #pragma unroll
          for (int f=0;f<NF;f++){
            float xv = xs[n*NF+f];
            float4 wv = *(const float4*)&W1s[f*64 + 4*ht];
            a0 += xv*wv.x; a1 += xv*wv.y; a2 += xv*wv.z; a3 += xv*wv.w;
          }
          h1T[(4*ht+0)*H1S+n]=a0; h1T[(4*ht+1)*H1S+n]=a1;
          h1T[(4*ht+2)*H1S+n]=a2; h1T[(4*ht+3)*H1S+n]=a3;
        }
      }
    }
  }
  __syncthreads();

  {
    int h = tid & 63, grp = tid >> 6;
    float ps = 0.f;
    for (int n=grp; n<NN; n+=4) ps += h1T[h*H1S+n];
    atomicAdd(&S1[h], ps);
  }
  __syncthreads();

  for (int e=tid; e<64*NN; e+=256){
    int h = e/NN, n = e - h*NN;
    float v = (h1T[h*H1S+n] + S1[h])*inv + b1s[h];
    h1T[h*H1S+n] = v>0.f ? v : 0.f;
  }
  __syncthreads();

  float acc[4][16];
  #pragma unroll
  for (int p=0;p<4;p++){
    #pragma unroll
    for (int e=0;e<16;e++) acc[p][e]=0.f;
    int tile = p*256 + tid;
    if (tile < 832){
      int nt = tile>>4, ht = tile&15;
      const float* arow = h1T + 4*nt;
      const float* wrow = W2s + 4*ht;
      #pragma unroll 4
      for (int k=0;k<64;k++){
        float4 a = *(const float4*)(arow + k*H1S);
        float4 w = *(const float4*)(wrow + k*64);
        acc[p][ 0] += a.x*w.x; acc[p][ 1] += a.x*w.y; acc[p][ 2] += a.x*w.z; acc[p][ 3] += a.x*w.w;
        acc[p][ 4] += a.y*w.x; acc[p][ 5] += a.y*w.y; acc[p][ 6] += a.y*w.z; acc[p][ 7] += a.y*w.w;
        acc[p][ 8] += a.z*w.x; acc[p][ 9] += a.z*w.y; acc[p][10] += a.z*w.z; acc[p][11] += a.z*w.w;
        acc[p][12] += a.w*w.x; acc[p][13] += a.w*w.y; acc[p][14] += a.w*w.z; acc[p][15] += a.w*w.w;
      }
      #pragma unroll
      for (int j=0;j<4;j++){
        float ps = acc[p][j] + acc[p][4+j] + acc[p][8+j] + acc[p][12+j];
        atomicAdd(&S2[4*ht+j], ps);
      }
    }
  }
  __syncthreads();

  const size_t outbase = ((size_t)b*NN)*SEQ_STRIDE + (size_t)t*NH;
  #pragma unroll
  for (int p=0;p<4;p++){
    int tile = p*256 + tid;
    if (tile < 832){
      int nt = tile>>4, ht = tile&15;
      #pragma unroll
      for (int i=0;i<4;i++){
        int n = 4*nt+i;
        if (n < NN){
          float4 o;
          float v0 = (acc[p][i*4+0] + S2[4*ht+0])*inv + b2s[4*ht+0];
          float v1 = (acc[p][i*4+1] + S2[4*ht+1])*inv + b2s[4*ht+1];
          float v2 = (acc[p][i*4+2] + S2[4*ht+2])*inv + b2s[4*ht+2];
          float v3 = (acc[p][i*4+3] + S2[4*ht+3])*inv + b2s[4*ht+3];
          o.x = v0>0.f?v0:0.f; o.y = v1>0.f?v1:0.f; o.z = v2>0.f?v2:0.f; o.w = v3>0.f?v3:0.f;
          *(float4*)&seqx[outbase + (size_t)n*SEQ_STRIDE + 4*ht] = o;
        }
      }
    }
  }
}

// ---------------- LSTM v2: gate-in-register, weights in LDS ----------------
// 255 blocks x 256 threads. Block owns 52 seqs. Thread (d = tid&63, sq = tid>>6)
// owns gates {d, d+64, d+128, d+192} for seqs sq*13 .. sq*13+12.
// Gates accumulate in VGPRs; c[13] lives in VGPRs across all 48 steps; only h
// round-trips LDS. Weights staged once: W[k][d][4 types] so one b128 read per
// (k,d) feeds 16 FMAs; x/h reads are wave-uniform broadcasts (conflict-free).
#define SBLK 52
#define LBLK 255
#define XHS 68   // row stride (floats) for xb/hb: 16B-aligned rows, bank-spread writes
#define LSTM2_LDS_FLOATS (16384*2 + SBLK*XHS*2)   // 159360 B

__device__ __forceinline__ float fsig(float x){
  return 1.0f/(1.0f + __expf(-x));
}
__device__ __forceinline__ float ftanh(float x){
  x = fminf(15.0f, fmaxf(-15.0f, x));
  float e = __expf(2.0f*x);
  return (e - 1.0f)/(e + 1.0f);
}

__global__ __launch_bounds__(256, 1) void lstm2_kernel(
    const float* __restrict__ seqx, const float* __restrict__ Wih, const float* __restrict__ Whh,
    const float* __restrict__ bih, const float* __restrict__ bhh,
    const float* __restrict__ Wfc, const float* __restrict__ bfc, float* __restrict__ out)
{
  extern __shared__ float sm[];
  float* Wx = sm;              // [64 k][64 d][4 ty]
  float* Wh = Wx + 16384;      // [64 k][64 d][4 ty]
  float* xb = Wh + 16384;      // [52][68]
  float* hb = xb + SBLK*XHS;   // [52][68]

  const int tid = threadIdx.x;
  const int d = tid & 63, sq = tid >> 6;
  const int s0 = blockIdx.x * SBLK;

  // ---- stage weights: thread g=tid owns source row g of each matrix ----
  {
    const int dd = tid & 63, ty = tid >> 6;
    const float* ri = Wih + tid*64;
    const float* rh = Whh + tid*64;
    #pragma unroll 4
    for (int k=0;k<64;k++){
      Wx[((k*64 + dd)<<2) + ty] = ri[k];
      Wh[((k*64 + dd)<<2) + ty] = rh[k];
    }
  }
  // zero h
  for (int i=tid;i<SBLK*XHS;i+=256) hb[i]=0.f;
  // stage x for t=0: thread -> (seq = tid>>2, part = tid&3), 16 floats each
  {
    const int ss = tid>>2, pt = tid&3;
    if (ss < SBLK){
      float4* dp = (float4*)(xb + ss*XHS + pt*16);
      if (s0 + ss < NSEQ){
        const float4* gp = (const float4*)(seqx + (size_t)(s0+ss)*SEQ_STRIDE + pt*16);
        dp[0]=gp[0]; dp[1]=gp[1]; dp[2]=gp[2]; dp[3]=gp[3];
      } else {
        float4 z = {0.f,0.f,0.f,0.f};
        dp[0]=z; dp[1]=z; dp[2]=z; dp[3]=z;
      }
    }
  }

  // per-thread bias for gates {d, d+64, d+128, d+192}
  const float bi0 = bih[d     ] + bhh[d     ];
  const float bi1 = bih[d+ 64 ] + bhh[d+ 64 ];
  const float bi2 = bih[d+128 ] + bhh[d+128 ];
  const float bi3 = bih[d+192 ] + bhh[d+192 ];

  float c[13];
  #pragma unroll
  for (int s=0;s<13;s++) c[s]=0.f;

  const float* xrow = xb + (sq*13)*XHS;
  const float* hrow = hb + (sq*13)*XHS;
  __syncthreads();

  for (int t=0;t<NT;t++){
    float acc[13][4];
    #pragma unroll
    for (int s=0;s<13;s++){ acc[s][0]=bi0; acc[s][1]=bi1; acc[s][2]=bi2; acc[s][3]=bi3; }

    // x-part: gates += x_t @ W_ih^T
    #pragma unroll 2
    for (int kb=0;kb<16;kb++){
      const float* wp = Wx + ((kb*4)*64 + d)*4;
      float4 w0 = *(const float4*)(wp          );
      float4 w1 = *(const float4*)(wp + 256    );
      float4 w2 = *(const float4*)(wp + 512    );
      float4 w3 = *(const float4*)(wp + 768    );
      #pragma unroll
      for (int s=0;s<13;s++){
        float4 v = *(const float4*)(xrow + s*XHS + kb*4);
        acc[s][0] += v.x*w0.x + v.y*w1.x + v.z*w2.x + v.w*w3.x;
        acc[s][1] += v.x*w0.y + v.y*w1.y + v.z*w2.y + v.w*w3.y;
        acc[s][2] += v.x*w0.z + v.y*w1.z + v.z*w2.z + v.w*w3.z;
        acc[s][3] += v.x*w0.w + v.y*w1.w + v.z*w2.w + v.w*w3.w;
      }
    }
    // h-part: gates += h_{t-1} @ W_hh^T
    #pragma unroll 2
    for (int kb=0;kb<16;kb++){
      const float* wp = Wh + ((kb*4)*64 + d)*4;
      float4 w0 = *(const float4*)(wp          );
      float4 w1 = *(const float4*)(wp + 256    );
      float4 w2 = *(const float4*)(wp + 512    );
      float4 w3 = *(const float4*)(wp + 768    );
      #pragma unroll
      for (int s=0;s<13;s++){
        float4 v = *(const float4*)(hrow + s*XHS + kb*4);
        acc[s][0] += v.x*w0.x + v.y*w1.x + v.z*w2.x + v.w*w3.x;
        acc[s][1] += v.x*w0.y + v.y*w1.y + v.z*w2.y + v.w*w3.y;
        acc[s][2] += v.x*w0.z + v.y*w1.z + v.z*w2.z + v.w*w3.z;
        acc[s][3] += v.x*w0.w + v.y*w1.w + v.z*w2.w + v.w*w3.w;
      }
    }
    __syncthreads();   // all x/h reads done

    // update: i,f,g,o are already in this thread's registers
    #pragma unroll
    for (int s=0;s<13;s++){
      float ig = fsig(acc[s][0]);
      float fg = fsig(acc[s][1]);
      float gt = ftanh(acc[s][2]);
      float og = fsig(acc[s][3]);
      float cc = fg*c[s] + ig*gt;
      c[s] = cc;
      hb[(sq*13+s)*XHS + d] = og*ftanh(cc);
    }
    // stage x for t+1 (xb readers finished at the barrier above)
    if (t+1 < NT){
      const int ss = tid>>2, pt = tid&3;
      if (ss < SBLK){
        float4* dp = (float4*)(xb + ss*XHS + pt*16);
        if (s0 + ss < NSEQ){
          const float4* gp = (const float4*)(seqx + (size_t)(s0+ss)*SEQ_STRIDE + (size_t)(t+1)*NH + pt*16);
          dp[0]=gp[0]; dp[1]=gp[1]; dp[2]=gp[2]; dp[3]=gp[3];
        } else {
          float4 z = {0.f,0.f,0.f,0.f};
          dp[0]=z; dp[1]=z; dp[2]=z; dp[3]=z;
        }
      }
    }
    __syncthreads();   // h/x ready for next step
  }

  // epilogue: out[seq] = h_T . W_fc + b_fc
  if (tid < SBLK && s0 + tid < NSEQ){
    float a = bfc[0];
    const float* hp = hb + tid*XHS;
    #pragma unroll 8
    for (int k=0;k<64;k++) a += hp[k]*Wfc[k];
    out[s0+tid] = a;
  }
}

extern "C" void kernel_launch(void* const* d_in, const int* in_sizes, int n_in,
                              void* d_out, int out_size, void* d_ws, size_t ws_size,
                              hipStream_t stream) {
  const float* x   = (const float*)d_in[0];
  // d_in[1], d_in[2] (N1, N2): structurally dead — sigmoid(N1@N2)>0 is all-ones.
  const float* W1  = (const float*)d_in[3];
  const float* b1  = (const float*)d_in[4];
  const float* W2  = (const float*)d_in[5];
  const float* b2  = (const float*)d_in[6];
  const float* Wih = (const float*)d_in[7];
  const float* Whh = (const float*)d_in[8];
  const float* bih = (const float*)d_in[9];
  const float* bhh = (const float*)d_in[10];
  const float* Wfc = (const float*)d_in[11];
  const float* bfc = (const float*)d_in[12];
  float* seqx = (float*)d_ws;           // [13248 seq][48 t][64 h] fp32 = 162.8 MB
  float* out  = (float*)d_out;

  const int gcn_lds  = GCN_LDS_FLOATS  * 4;
  const int lstm_lds = LSTM2_LDS_FLOATS * 4;   // 159360 B
  hipFuncSetAttribute((const void*)gcn_kernel,   hipFuncAttributeMaxDynamicSharedMemorySize, gcn_lds);
  hipFuncSetAttribute((const void*)lstm2_kernel, hipFuncAttributeMaxDynamicSharedMemorySize, lstm_lds);

  gcn_kernel<<<dim3(NT, NB), 256, gcn_lds, stream>>>(x, W1, b1, W2, b2, seqx);
  lstm2_kernel<<<LBLK, 256, lstm_lds, stream>>>(seqx, Wih, Whh, bih, bhh, Wfc, bfc, out);
}